// Round 2
// baseline (2798.652 us; speedup 1.0000x reference)
//
#include <hip/hip_runtime.h>
#include <hip/hip_bf16.h>

// Problem constants (from reference): B=4,S=2048,H=2048,G=4,E=8,D=512,TOP_K=2
#define T_TOK   8192      // B*S
#define HDIM    2048
#define DDIM    512
#define NGROUP  4
#define NEXP    8
#define NGE     32        // NGROUP*NEXP
#define CAP     8192      // worst-case tokens per (g,e) list

// ---------------------------------------------------------------------------
// Gating: one block per token. Stage x row (8 KiB) in LDS; wave g computes the
// 8 expert logits for group g via lane-strided float4 dots + shuffle reduce.
// Lane 0 picks top-2 (stable tie-break = lower index, matching jax.lax.top_k),
// computes renormalized weights w0=1/(1+exp(l1-l0)), appends to per-(g,e)
// token lists with atomicAdd on counts.
// ---------------------------------------------------------------------------
__global__ __launch_bounds__(256) void gating_kernel(
    const float* __restrict__ x, const float* __restrict__ gate_w,
    int* __restrict__ counts, int* __restrict__ ltok, float* __restrict__ lw) {
  const int t = blockIdx.x;
  __shared__ float xsm[HDIM];
  const int tid = threadIdx.x;
  const float4* xv = (const float4*)(x + (size_t)t * HDIM);
  float4* xsv = (float4*)xsm;
  for (int i = tid; i < HDIM / 4; i += 256) xsv[i] = xv[i];
  __syncthreads();

  const int g = tid >> 6;     // wave index = group
  const int lane = tid & 63;
  const float* gw = gate_w + (size_t)g * NEXP * HDIM;

  float logits[NEXP];
#pragma unroll
  for (int e = 0; e < NEXP; e++) {
    const float4* gv = (const float4*)(gw + e * HDIM);
    float s = 0.f;
#pragma unroll
    for (int i = lane; i < HDIM / 4; i += 64) {
      float4 a = xsv[i], b = gv[i];
      s += a.x * b.x + a.y * b.y + a.z * b.z + a.w * b.w;
    }
#pragma unroll
    for (int off = 32; off > 0; off >>= 1) s += __shfl_xor(s, off);
    logits[e] = s;
  }

  if (lane == 0) {
    int i0 = 0; float l0 = logits[0];
#pragma unroll
    for (int e = 1; e < NEXP; e++)
      if (logits[e] > l0) { l0 = logits[e]; i0 = e; }
    int i1 = -1; float l1 = -1e30f;
#pragma unroll
    for (int e = 0; e < NEXP; e++) {
      if (e == i0) continue;
      if (logits[e] > l1) { l1 = logits[e]; i1 = e; }
    }
    // softmax -> top2 -> renormalize  ==  pairwise sigmoid of logit gap
    float w0 = 1.f / (1.f + expf(l1 - l0));
    float w1 = 1.f - w0;
    int ge0 = (g << 3) + i0;
    int ge1 = (g << 3) + i1;
    int p0 = atomicAdd(&counts[ge0], 1);
    ltok[ge0 * CAP + p0] = t; lw[ge0 * CAP + p0] = w0;
    int p1 = atomicAdd(&counts[ge1], 1);
    ltok[ge1 * CAP + p1] = t; lw[ge1 * CAP + p1] = w1;
  }
}

// ---------------------------------------------------------------------------
// Gathered expert GEMM. Grid (token_tiles=64, d_tiles=4, ge=32); blocks past
// the list length exit early. Tile: 128 tokens x 128 d, BK=32, 256 threads,
// 8x8 accumulators/thread. LDS is k-major (xs[kk][slot]) so compute-side
// reads are float4 with <=2-way bank aliasing (free). Epilogue atomically
// accumulates 0.25*rw*(acc + bias) into avg_out[t][d].
// ---------------------------------------------------------------------------
__global__ __launch_bounds__(256) void expert_gemm(
    const float* __restrict__ x, const float* __restrict__ expert_w,
    const float* __restrict__ expert_b, const int* __restrict__ counts,
    const int* __restrict__ ltok, const float* __restrict__ lw,
    float* __restrict__ avg_out) {
  const int ge = blockIdx.z;
  const int cnt = counts[ge];
  const int t0 = blockIdx.x * 128;
  if (t0 >= cnt) return;
  const int d0 = blockIdx.y * 128;

  __shared__ float xs[32][128];
  __shared__ float ws[32][128];
  __shared__ int   stok[128];
  __shared__ float srw[128];

  const int tid = threadIdx.x;
  if (tid < 128) {
    int idx = t0 + tid;
    if (idx < cnt) { stok[tid] = ltok[ge * CAP + idx]; srw[tid] = lw[ge * CAP + idx]; }
    else           { stok[tid] = -1;                   srw[tid] = 0.f; }
  }
  __syncthreads();

  // staging mapping: each thread loads 16 contiguous floats (64B) of one row
  const int srow = tid >> 1;          // 0..127  (token slot / d row)
  const int shalf = (tid & 1) * 16;   // which 16 floats of the 32-wide k tile
  int tok = stok[srow]; if (tok < 0) tok = 0;
  const float* xrow = x + (size_t)tok * HDIM + shalf;
  const float* wrow = expert_w + ((size_t)ge * DDIM + (d0 + srow)) * HDIM + shalf;

  const int tr = tid >> 4;   // 0..15 -> token slots tr*4+i, 64+tr*4+i
  const int tc = tid & 15;   // 0..15 -> d offsets   tc*4+j, 64+tc*4+j

  float acc[8][8];
#pragma unroll
  for (int i = 0; i < 8; i++)
#pragma unroll
    for (int j = 0; j < 8; j++) acc[i][j] = 0.f;

  for (int h0 = 0; h0 < HDIM; h0 += 32) {
    float4 a0 = *(const float4*)(xrow + h0);
    float4 a1 = *(const float4*)(xrow + h0 + 4);
    float4 a2 = *(const float4*)(xrow + h0 + 8);
    float4 a3 = *(const float4*)(xrow + h0 + 12);
    float4 b0 = *(const float4*)(wrow + h0);
    float4 b1 = *(const float4*)(wrow + h0 + 4);
    float4 b2 = *(const float4*)(wrow + h0 + 8);
    float4 b3 = *(const float4*)(wrow + h0 + 12);
    __syncthreads();  // previous tile's compute done before overwrite
    xs[shalf + 0][srow] = a0.x;  xs[shalf + 1][srow] = a0.y;
    xs[shalf + 2][srow] = a0.z;  xs[shalf + 3][srow] = a0.w;
    xs[shalf + 4][srow] = a1.x;  xs[shalf + 5][srow] = a1.y;
    xs[shalf + 6][srow] = a1.z;  xs[shalf + 7][srow] = a1.w;
    xs[shalf + 8][srow] = a2.x;  xs[shalf + 9][srow] = a2.y;
    xs[shalf + 10][srow] = a2.z; xs[shalf + 11][srow] = a2.w;
    xs[shalf + 12][srow] = a3.x; xs[shalf + 13][srow] = a3.y;
    xs[shalf + 14][srow] = a3.z; xs[shalf + 15][srow] = a3.w;
    ws[shalf + 0][srow] = b0.x;  ws[shalf + 1][srow] = b0.y;
    ws[shalf + 2][srow] = b0.z;  ws[shalf + 3][srow] = b0.w;
    ws[shalf + 4][srow] = b1.x;  ws[shalf + 5][srow] = b1.y;
    ws[shalf + 6][srow] = b1.z;  ws[shalf + 7][srow] = b1.w;
    ws[shalf + 8][srow] = b2.x;  ws[shalf + 9][srow] = b2.y;
    ws[shalf + 10][srow] = b2.z; ws[shalf + 11][srow] = b2.w;
    ws[shalf + 12][srow] = b3.x; ws[shalf + 13][srow] = b3.y;
    ws[shalf + 14][srow] = b3.z; ws[shalf + 15][srow] = b3.w;
    __syncthreads();

#pragma unroll 8
    for (int kk = 0; kk < 32; kk++) {
      float av[8], bv[8];
      *(float4*)(av)     = *(const float4*)(&xs[kk][tr * 4]);
      *(float4*)(av + 4) = *(const float4*)(&xs[kk][64 + tr * 4]);
      *(float4*)(bv)     = *(const float4*)(&ws[kk][tc * 4]);
      *(float4*)(bv + 4) = *(const float4*)(&ws[kk][64 + tc * 4]);
#pragma unroll
      for (int i = 0; i < 8; i++)
#pragma unroll
        for (int j = 0; j < 8; j++) acc[i][j] += av[i] * bv[j];
    }
  }

  // epilogue: weighted accumulation into avg_out (1/G factor folded in)
#pragma unroll
  for (int i = 0; i < 8; i++) {
    int slot = (i < 4) ? (tr * 4 + i) : (64 + tr * 4 + (i - 4));
    int tk = stok[slot];
    if (tk < 0) continue;
    float rwv = srw[slot] * 0.25f;
#pragma unroll
    for (int j = 0; j < 8; j++) {
      int d = d0 + ((j < 4) ? (tc * 4 + j) : (64 + tc * 4 + (j - 4)));
      float val = (acc[i][j] + expert_b[ge * DDIM + d]) * rwv;
      atomicAdd(&avg_out[(size_t)tk * DDIM + d], val);
    }
  }
}

// ---------------------------------------------------------------------------
// Final: out[t][j] = x[t]·orig_w[j] + orig_b[j] + avg_out[t]·agg_w[j] + agg_b[j]
// One block per token; wave j handles output j.
// ---------------------------------------------------------------------------
__global__ __launch_bounds__(256) void final_kernel(
    const float* __restrict__ x, const float* __restrict__ avg_out,
    const float* __restrict__ agg_w, const float* __restrict__ agg_b,
    const float* __restrict__ orig_w, const float* __restrict__ orig_b,
    float* __restrict__ out) {
  const int t = blockIdx.x;
  const int tid = threadIdx.x;
  __shared__ float xsm[HDIM];
  const float4* xv = (const float4*)(x + (size_t)t * HDIM);
  float4* xsv = (float4*)xsm;
  for (int i = tid; i < HDIM / 4; i += 256) xsv[i] = xv[i];
  __syncthreads();

  const int j = tid >> 6;    // wave = output column
  const int lane = tid & 63;

  const float4* ov = (const float4*)(orig_w + (size_t)j * HDIM);
  float s = 0.f;
#pragma unroll
  for (int i = lane; i < HDIM / 4; i += 64) {
    float4 a = xsv[i], b = ov[i];
    s += a.x * b.x + a.y * b.y + a.z * b.z + a.w * b.w;
  }
  const float4* av = (const float4*)(avg_out + (size_t)t * DDIM);
  const float4* gv = (const float4*)(agg_w + (size_t)j * DDIM);
#pragma unroll
  for (int i = lane; i < DDIM / 4; i += 64) {
    float4 a = av[i], b = gv[i];
    s += a.x * b.x + a.y * b.y + a.z * b.z + a.w * b.w;
  }
#pragma unroll
  for (int off = 32; off > 0; off >>= 1) s += __shfl_xor(s, off);
  if (lane == 0) out[(size_t)t * NGROUP + j] = s + orig_b[j] + agg_b[j];
}

// ---------------------------------------------------------------------------
extern "C" void kernel_launch(void* const* d_in, const int* in_sizes, int n_in,
                              void* d_out, int out_size, void* d_ws, size_t ws_size,
                              hipStream_t stream) {
  const float* x        = (const float*)d_in[0];
  const float* gate_w   = (const float*)d_in[1];
  const float* expert_w = (const float*)d_in[2];
  const float* expert_b = (const float*)d_in[3];
  const float* agg_w    = (const float*)d_in[4];
  const float* agg_b    = (const float*)d_in[5];
  const float* orig_w   = (const float*)d_in[6];
  const float* orig_b   = (const float*)d_in[7];
  float* out = (float*)d_out;

  // workspace layout (~19 MiB): avg_out | counts | ltok | lw
  char* ws = (char*)d_ws;
  float* avg_out = (float*)ws;
  int*   counts  = (int*)(ws + (size_t)T_TOK * DDIM * sizeof(float));
  int*   ltok    = counts + NGE;
  float* lwt     = (float*)(ltok + NGE * CAP);

  hipMemsetAsync(counts, 0, NGE * sizeof(int), stream);
  hipMemsetAsync(avg_out, 0, (size_t)T_TOK * DDIM * sizeof(float), stream);

  gating_kernel<<<T_TOK, 256, 0, stream>>>(x, gate_w, counts, ltok, lwt);

  dim3 eg(T_TOK / 128, DDIM / 128, NGE);  // early-exit on token tiles past count
  expert_gemm<<<eg, 256, 0, stream>>>(x, expert_w, expert_b, counts, ltok, lwt, avg_out);

  final_kernel<<<T_TOK, 256, 0, stream>>>(x, avg_out, agg_w, agg_b, orig_w, orig_b, out);
}

// Round 4
// 1112.931 us; speedup vs baseline: 2.5147x; 2.5147x over previous
//
#include <hip/hip_runtime.h>
#include <hip/hip_bf16.h>

// Problem constants: B=4,S=2048,H=2048,G=4,E=8,D=512,TOP_K=2
#define T_TOK   8192
#define HDIM    2048
#define DDIM    512
#define NGROUP  4
#define NEXP    8
#define NGE     32
#define CAP     8192

typedef __attribute__((ext_vector_type(8))) short short8;
typedef __attribute__((ext_vector_type(4))) float f32x4;

struct alignas(16) U8 { ushort u[8]; };

__device__ __forceinline__ ushort f2bf(float f) {
  union { __hip_bfloat16 h; ushort u; } c;
  c.h = __float2bfloat16(f);
  return c.u;
}

__device__ __forceinline__ void gload16(const void* g, void* l) {
  __builtin_amdgcn_global_load_lds(
      (const __attribute__((address_space(1))) void*)g,
      (__attribute__((address_space(3))) void*)l, 16, 0, 0);
}

// ---------------------------------------------------------------------------
// Gating (fp32, exact routing) + fused x -> bf16 conversion.
// One block per token; wave g computes group g's 8 logits.
// ---------------------------------------------------------------------------
__global__ __launch_bounds__(256) void gating_kernel(
    const float* __restrict__ x, const float* __restrict__ gate_w,
    int* __restrict__ counts, int* __restrict__ ltok, float* __restrict__ lw,
    ushort* __restrict__ xbf) {
  const int t = blockIdx.x;
  __shared__ float xsm[HDIM];
  const int tid = threadIdx.x;
  const float4* xv = (const float4*)(x + (size_t)t * HDIM);
  float4* xsv = (float4*)xsm;
  for (int i = tid; i < HDIM / 4; i += 256) xsv[i] = xv[i];
  __syncthreads();

  // fused bf16 conversion of this token's row (8 elems/thread, one 16B store)
  {
    U8 pack;
#pragma unroll
    for (int j = 0; j < 8; j++) pack.u[j] = f2bf(xsm[tid * 8 + j]);
    *(U8*)(xbf + (size_t)t * HDIM + tid * 8) = pack;
  }

  const int g = tid >> 6;
  const int lane = tid & 63;
  const float* gw = gate_w + (size_t)g * NEXP * HDIM;

  float logits[NEXP];
#pragma unroll
  for (int e = 0; e < NEXP; e++) {
    const float4* gv = (const float4*)(gw + e * HDIM);
    float s = 0.f;
#pragma unroll
    for (int i = lane; i < HDIM / 4; i += 64) {
      float4 a = xsv[i], b = gv[i];
      s += a.x * b.x + a.y * b.y + a.z * b.z + a.w * b.w;
    }
#pragma unroll
    for (int off = 32; off > 0; off >>= 1) s += __shfl_xor(s, off);
    logits[e] = s;
  }

  if (lane == 0) {
    int i0 = 0; float l0 = logits[0];
#pragma unroll
    for (int e = 1; e < NEXP; e++)
      if (logits[e] > l0) { l0 = logits[e]; i0 = e; }
    int i1 = -1; float l1 = -1e30f;
#pragma unroll
    for (int e = 0; e < NEXP; e++) {
      if (e == i0) continue;
      if (logits[e] > l1) { l1 = logits[e]; i1 = e; }
    }
    float w0 = 1.f / (1.f + expf(l1 - l0));   // softmax->top2->renorm, exact
    float w1 = 1.f - w0;
    int ge0 = (g << 3) + i0;
    int ge1 = (g << 3) + i1;
    int p0 = atomicAdd(&counts[ge0], 1);
    ltok[ge0 * CAP + p0] = t; lw[ge0 * CAP + p0] = w0;
    int p1 = atomicAdd(&counts[ge1], 1);
    ltok[ge1 * CAP + p1] = t; lw[ge1 * CAP + p1] = w1;
  }
}

// ---------------------------------------------------------------------------
// expert_w fp32 -> bf16 (33.5M elems, 8/thread)
// ---------------------------------------------------------------------------
__global__ __launch_bounds__(256) void convert_w(
    const float* __restrict__ w, ushort* __restrict__ wbf) {
  const int i = (blockIdx.x * 256 + threadIdx.x) * 8;
  float4 f0 = *(const float4*)(w + i);
  float4 f1 = *(const float4*)(w + i + 4);
  U8 pack;
  pack.u[0] = f2bf(f0.x); pack.u[1] = f2bf(f0.y);
  pack.u[2] = f2bf(f0.z); pack.u[3] = f2bf(f0.w);
  pack.u[4] = f2bf(f1.x); pack.u[5] = f2bf(f1.y);
  pack.u[6] = f2bf(f1.z); pack.u[7] = f2bf(f1.w);
  *(U8*)(wbf + i) = pack;
}

// ---------------------------------------------------------------------------
// Gathered bf16 MFMA expert GEMM.
// Tile 128 tokens x 128 d, BK=64 bf16, 256 thr = 4 waves (2x2, each 64x64).
// Staging: global_load_lds 16B with pre-swizzled per-lane global source ->
// linear LDS dest; ds_read_b128 with matching XOR swizzle (conflict-free:
// granule = (koct ^ (row&7)) spans all 8 4-bank groups evenly, 8 lanes each).
// Epilogue: atomicAdd 0.25*rw*(acc+bias) into avg_out.
// ---------------------------------------------------------------------------
__global__ __launch_bounds__(256, 4) void expert_gemm_bf16(
    const ushort* __restrict__ xbf, const ushort* __restrict__ wbf,
    const float* __restrict__ expert_b, const int* __restrict__ counts,
    const int* __restrict__ ltok, const float* __restrict__ lw,
    float* __restrict__ avg_out) {
  const int ge = blockIdx.z;
  const int cnt = counts[ge];
  const int t0 = blockIdx.x * 128;
  if (t0 >= cnt) return;
  const int d0 = blockIdx.y * 128;

  __shared__ ushort As[128 * 64];   // [row][k], 128B rows, XOR-swizzled content
  __shared__ ushort Bs[128 * 64];
  __shared__ int   stok[128];
  __shared__ float srw[128];

  const int tid = threadIdx.x;
  const int w = tid >> 6, l = tid & 63;
  if (tid < 128) {
    int idx = t0 + tid;
    stok[tid] = (idx < cnt) ? ltok[ge * CAP + idx] : -1;
    srw[tid]  = (idx < cnt) ? lw[ge * CAP + idx] : 0.f;
  }
  __syncthreads();

  // staging: chunk c = i*4+w covers rows 8c..8c+7; lane l -> row 8c+(l>>3),
  // linear LDS byte c*1024 + l*16. Source row-byte pre-swizzled so that a
  // read at row-byte rb returns global byte rb ^ ((row&7)<<4).
  const int kSrc = (((l & 7) ^ (l >> 3)) << 4);
  const char* gaA[4];
  const char* gaB[4];
  uint32_t ldsOff[4];
#pragma unroll
  for (int i = 0; i < 4; i++) {
    int c = i * 4 + w;
    int r = c * 8 + (l >> 3);
    int tk = stok[r]; if (tk < 0) tk = 0;
    gaA[i] = (const char*)(xbf + (size_t)tk * HDIM) + kSrc;
    gaB[i] = (const char*)(wbf + ((size_t)ge * DDIM + d0 + r) * HDIM) + kSrc;
    ldsOff[i] = (uint32_t)c * 1024;   // wave-uniform (c depends on i,w only)
  }

  const int wr = w >> 1, wc = w & 1;
  const int arow = wr * 64 + (l & 15);     // A frag row base (token slot)
  const int brow = wc * 64 + (l & 15);     // B frag row base (d)
  const int swz = (l & 7) << 4;            // row&7 == l&7 for frag rows
  const int koct = (l >> 4) * 16;          // byte offset of lane's k-octet

  f32x4 acc[4][4];
#pragma unroll
  for (int m = 0; m < 4; m++)
#pragma unroll
    for (int n = 0; n < 4; n++) acc[m][n] = (f32x4)0.f;

  for (int h = 0; h < HDIM * 2; h += 128) {   // 128B = 64 bf16 per K-step
#pragma unroll
    for (int i = 0; i < 4; i++) gload16(gaA[i] + h, (char*)As + ldsOff[i]);
#pragma unroll
    for (int i = 0; i < 4; i++) gload16(gaB[i] + h, (char*)Bs + ldsOff[i]);
    __syncthreads();   // compiler drains vmcnt before barrier

#pragma unroll
    for (int ks = 0; ks < 2; ks++) {
      const int kb = ks * 64 + koct;
      short8 a[4], b[4];
#pragma unroll
      for (int m = 0; m < 4; m++)
        a[m] = *(const short8*)((const char*)As + (arow + m * 16) * 128 + (kb ^ swz));
#pragma unroll
      for (int n = 0; n < 4; n++)
        b[n] = *(const short8*)((const char*)Bs + (brow + n * 16) * 128 + (kb ^ swz));
#pragma unroll
      for (int m = 0; m < 4; m++)
#pragma unroll
        for (int n = 0; n < 4; n++)
          acc[m][n] = __builtin_amdgcn_mfma_f32_16x16x32_bf16(a[m], b[n], acc[m][n], 0, 0, 0);
    }
    __syncthreads();
  }

  // epilogue: D row = (l>>4)*4+reg (token slot), col = l&15 (d)  [m89 layout]
#pragma unroll
  for (int m = 0; m < 4; m++) {
#pragma unroll
    for (int reg = 0; reg < 4; reg++) {
      int slot = wr * 64 + m * 16 + (l >> 4) * 4 + reg;
      int tk = stok[slot];
      if (tk < 0) continue;
      float rwv = srw[slot] * 0.25f;
#pragma unroll
      for (int n = 0; n < 4; n++) {
        int d = d0 + wc * 64 + n * 16 + (l & 15);
        float v = (acc[m][n][reg] + expert_b[ge * DDIM + d]) * rwv;
        atomicAdd(&avg_out[(size_t)tk * DDIM + d], v);
      }
    }
  }
}

// ---------------------------------------------------------------------------
// Final: out[t][j] = x[t]·orig_w[j] + orig_b[j] + avg_out[t]·agg_w[j] + agg_b[j]
// ---------------------------------------------------------------------------
__global__ __launch_bounds__(256) void final_kernel(
    const float* __restrict__ x, const float* __restrict__ avg_out,
    const float* __restrict__ agg_w, const float* __restrict__ agg_b,
    const float* __restrict__ orig_w, const float* __restrict__ orig_b,
    float* __restrict__ out) {
  const int t = blockIdx.x;
  const int tid = threadIdx.x;
  __shared__ float xsm[HDIM];
  const float4* xv = (const float4*)(x + (size_t)t * HDIM);
  float4* xsv = (float4*)xsm;
  for (int i = tid; i < HDIM / 4; i += 256) xsv[i] = xv[i];
  __syncthreads();

  const int j = tid >> 6;
  const int lane = tid & 63;

  const float4* ov = (const float4*)(orig_w + (size_t)j * HDIM);
  float s = 0.f;
#pragma unroll
  for (int i = lane; i < HDIM / 4; i += 64) {
    float4 a = xsv[i], b = ov[i];
    s += a.x * b.x + a.y * b.y + a.z * b.z + a.w * b.w;
  }
  const float4* av = (const float4*)(avg_out + (size_t)t * DDIM);
  const float4* gv = (const float4*)(agg_w + (size_t)j * DDIM);
#pragma unroll
  for (int i = lane; i < DDIM / 4; i += 64) {
    float4 a = av[i], b = gv[i];
    s += a.x * b.x + a.y * b.y + a.z * b.z + a.w * b.w;
  }
#pragma unroll
  for (int off = 32; off > 0; off >>= 1) s += __shfl_xor(s, off);
  if (lane == 0) out[(size_t)t * NGROUP + j] = s + orig_b[j] + agg_b[j];
}

// ---------------------------------------------------------------------------
extern "C" void kernel_launch(void* const* d_in, const int* in_sizes, int n_in,
                              void* d_out, int out_size, void* d_ws, size_t ws_size,
                              hipStream_t stream) {
  const float* x        = (const float*)d_in[0];
  const float* gate_w   = (const float*)d_in[1];
  const float* expert_w = (const float*)d_in[2];
  const float* expert_b = (const float*)d_in[3];
  const float* agg_w    = (const float*)d_in[4];
  const float* agg_b    = (const float*)d_in[5];
  const float* orig_w   = (const float*)d_in[6];
  const float* orig_b   = (const float*)d_in[7];
  float* out = (float*)d_out;

  // workspace layout (~115 MiB): avg_out | xbf | wbf | counts | ltok | lw
  char* ws = (char*)d_ws;
  float*  avg_out = (float*)ws;                                  // 16 MiB
  ushort* xbf     = (ushort*)(ws + (size_t)16 * 1024 * 1024);    // 32 MiB
  ushort* wbf     = (ushort*)(ws + (size_t)48 * 1024 * 1024);    // 64 MiB
  int*    counts  = (int*)(ws + (size_t)112 * 1024 * 1024);
  int*    ltok    = counts + NGE;
  float*  lwt     = (float*)(ltok + NGE * CAP);

  hipMemsetAsync(counts, 0, NGE * sizeof(int), stream);
  hipMemsetAsync(avg_out, 0, (size_t)T_TOK * DDIM * sizeof(float), stream);

  convert_w<<<(NGE * DDIM * HDIM) / (256 * 8), 256, 0, stream>>>(expert_w, wbf);
  gating_kernel<<<T_TOK, 256, 0, stream>>>(x, gate_w, counts, ltok, lwt, xbf);

  dim3 eg(T_TOK / 128, DDIM / 128, NGE);
  expert_gemm_bf16<<<eg, 256, 0, stream>>>(xbf, wbf, expert_b, counts, ltok, lwt, avg_out);

  final_kernel<<<T_TOK, 256, 0, stream>>>(x, avg_out, agg_w, agg_b, orig_w, orig_b, out);
}